// Round 5
// baseline (332.694 us; speedup 1.0000x reference)
//
#include <hip/hip_runtime.h>
#include <hip/hip_bf16.h>
#include <cstdint>
#include <cstddef>

typedef unsigned short u16;
typedef __attribute__((ext_vector_type(8))) short s8v;    // 8 x bf16 = 4 VGPR
typedef __attribute__((ext_vector_type(4))) float f4v;    // 16x16 MFMA acc
typedef __attribute__((ext_vector_type(8))) u16 u16x8;
typedef __attribute__((ext_vector_type(4))) uint32_t u32x4;

#define AS1 __attribute__((address_space(1)))
#define AS3 __attribute__((address_space(3)))

// ---- constants ----
#define BATCH 16
#define SEQ   1024
#define EMBED 768
#define HEADS 12
#define DH    64
#define MTOT  (BATCH*SEQ)       // 16384

__device__ __forceinline__ u16 f2bf(float f) {      // RNE fp32 -> bf16
    union { float f; uint32_t u; } v; v.f = f;
    uint32_t r = v.u + 0x7fffu + ((v.u >> 16) & 1u);
    return (u16)(r >> 16);
}

__device__ __forceinline__ void gll16(const u16* g, u16* l) {
    __builtin_amdgcn_global_load_lds((AS1 void*)g, (AS3 void*)l, 16, 0, 0);
}

// ---------------- fused pack: x -> bf16; weights transpose+bf16; biases ----------------
// Wq/bq pre-scaled by 0.125 (folds attention 1/sqrt(Dh) into Q proj).
#define XBLOCKS 12288
__global__ void k_pack(const float* __restrict__ x, u16* __restrict__ xb, int nx,
                       const float* __restrict__ Wq, const float* __restrict__ Wk,
                       const float* __restrict__ Wv, const float* __restrict__ Wo,
                       const float* __restrict__ bq, const float* __restrict__ bk,
                       const float* __restrict__ bv,
                       u16* __restrict__ wqkvT, u16* __restrict__ woT,
                       float* __restrict__ bqkv)
{
    if (blockIdx.x < XBLOCKS) {
        int i = (blockIdx.x * 256 + threadIdx.x) * 4;
        if (i + 3 < nx) {
            float4 f = *(const float4*)(x + i);
            ushort4 o;
            o.x = f2bf(f.x); o.y = f2bf(f.y); o.z = f2bf(f.z); o.w = f2bf(f.w);
            *(ushort4*)(xb + i) = o;
        }
        return;
    }
    const int NQKV = 2304 * 768;
    const int NO = 768 * 768;
    int t = (blockIdx.x - XBLOCKS) * 256 + threadIdx.x;
    if (t < NQKV) {
        int n = t % 2304, k = t / 2304;
        const float* src; int nn; float sc;
        if (n < 768)       { src = Wq; nn = n;        sc = 0.125f; }
        else if (n < 1536) { src = Wk; nn = n - 768;  sc = 1.0f;   }
        else               { src = Wv; nn = n - 1536; sc = 1.0f;   }
        wqkvT[(size_t)n * 768 + k] = f2bf(src[(size_t)k * 768 + nn] * sc);
    } else if (t < NQKV + NO) {
        int t2 = t - NQKV;
        int n = t2 % 768, k = t2 / 768;
        woT[(size_t)n * 768 + k] = f2bf(Wo[(size_t)k * 768 + n]);
    } else if (t < NQKV + NO + 2304) {
        int t3 = t - NQKV - NO;
        bqkv[t3] = (t3 < 768) ? bq[t3] * 0.125f
                 : ((t3 < 1536) ? bk[t3 - 768] : bv[t3 - 1536]);
    }
}

// ---------------- 8-phase 256x256 GEMM (round-5: fragment-carrying phases) --------
// BM=BN=256, BK=64, 512 thr = 8 waves (2M x 4N), per-wave C 128x64 = 8x4 frags.
// Data movement, swizzle, vmcnt ledger, deadness schedule, epilogue: identical to
// the round-3 kernel (verified correct). ONLY change: 24 ds_read_b128 per wave
// per K-tile instead of 48, via persistent fragment regs carried across phases:
//   PH1 (mh0,nh0): read aR=a(mh0) 8 + bR0=b(nh0) 4;  stage A-h1(s+1)
//   PH2 (mh0,nh1): read bR1=b(nh1) 4;                stage B-h1(s+1)
//   PH3 (mh1,nh0): read aR=a(mh1) 8 (overwrite);     stage A-h0(s+2)
//   PH4 (mh1,nh1): no reads;                         stage B-h0(s+2)
// Reg budget: acc 128 (AGPR) + frags 64 + misc ~ 250 <= 256 @ 2 waves/SIMD.
#define NT 12   // 768 / 64 K-tiles

template<int MODE>
__global__ __launch_bounds__(512, 2) void k_gemm8(
    const u16* __restrict__ A, const u16* __restrict__ BT,
    const float* __restrict__ bias,
    u16* __restrict__ oq, u16* __restrict__ okk, u16* __restrict__ ov,
    float* __restrict__ of, int NBN)
{
    __shared__ __attribute__((aligned(16))) u16 AB[2][16384];   // 64 KB
    __shared__ __attribute__((aligned(16))) u16 BB[2][16384];   // 64 KB

    // bijective XCD swizzle (gridDim.x % 8 == 0 for both launches)
    const int nwg = gridDim.x;
    const int bid = blockIdx.x;
    const int wg = (bid & 7) * (nwg >> 3) + (bid >> 3);
    const int bm = wg / NBN, bn = wg % NBN;
    const int m0 = bm * 256, n0 = bn * 256;

    const int tid = threadIdx.x, wv = tid >> 6;
    const int ln = tid & 63, l15 = ln & 15, quad = ln >> 4;
    const int wm = wv >> 2, wn = wv & 3;          // 2 x 4 wave grid

    // ---- staging source pointers (pre-swizzled global addresses) ----
    const int chnk = ((tid & 7) ^ ((tid >> 3) & 7)) * 8;
    const u16* pA = A + (size_t)(m0 + (tid >> 3)) * 768 + chnk;
    const u16* pB = BT + (size_t)(n0 + (tid >> 8) * 64 + ((tid >> 3) & 31)) * 768 + chnk;

#define STG_A(BUF, mh, kt) { \
    const u16* s_ = pA + (mh) * 49152 + (kt) * 64; \
    gll16(s_,          (BUF) + (mh) * 8192 + wv * 512); \
    gll16(s_ + 98304,  (BUF) + (mh) * 8192 + 4096 + wv * 512); }
#define STG_B(BUF, nh, kt) { \
    const u16* s_ = pB + (nh) * 24576 + (kt) * 64; \
    gll16(s_,          (BUF) + (nh) * 8192 + wv * 512); \
    gll16(s_ + 98304,  (BUF) + (nh) * 8192 + 4096 + wv * 512); }

    // ---- read-side offsets (u16 units) ----
    const int offA = wm * 4096 + l15 * 64;
    const int offB = wn * 2048 + l15 * 64;
    const int ph0 = ((quad)     ^ (l15 & 7)) * 8; // ks=0 chunk
    const int ph1 = ((4 + quad) ^ (l15 & 7)) * 8; // ks=1 chunk

    f4v acc[8][4] = {};
    s8v aR[4][2], bR0[2][2], bR1[2][2];

    // ---- prologue: tile 0 fully + tile 1 {A-h0, B-h0} (12 gll16 calls) ----
    STG_A(&AB[0][0], 0, 0); STG_B(&BB[0][0], 0, 0);
    STG_A(&AB[0][0], 1, 0); STG_B(&BB[0][0], 1, 0);
    STG_A(&AB[1][0], 0, 1); STG_B(&BB[1][0], 0, 1);

    for (int s = 0; s < NT; ++s) {
        const int cur = s & 1;
        u16* Acur = &AB[cur][0];
        u16* Bcur = &BB[cur][0];
        u16* Anxt = &AB[cur ^ 1][0];
        u16* Bnxt = &BB[cur ^ 1][0];

        // gate: this tile's 4 halves landed (4 newest loads = prefetch for s+1/s+2)
        if (s == NT - 1) { asm volatile("s_waitcnt vmcnt(0)" ::: "memory"); }
        else             { asm volatile("s_waitcnt vmcnt(4)" ::: "memory"); }
        __builtin_amdgcn_s_barrier();

        // ---- PH1: mh=0, nh=0 ----
#pragma unroll
        for (int i = 0; i < 4; ++i) {
            aR[i][0] = *(const s8v*)(Acur + offA + i * 1024 + ph0);
            aR[i][1] = *(const s8v*)(Acur + offA + i * 1024 + ph1);
        }
#pragma unroll
        for (int j = 0; j < 2; ++j) {
            bR0[j][0] = *(const s8v*)(Bcur + offB + j * 1024 + ph0);
            bR0[j][1] = *(const s8v*)(Bcur + offB + j * 1024 + ph1);
        }
        if (s < NT - 1) STG_A(Anxt, 1, s + 1);
        __builtin_amdgcn_s_barrier();
        __builtin_amdgcn_s_setprio(1);
#pragma unroll
        for (int i = 0; i < 4; ++i)
#pragma unroll
            for (int j = 0; j < 2; ++j) {
                acc[i][j] = __builtin_amdgcn_mfma_f32_16x16x32_bf16(aR[i][0], bR0[j][0], acc[i][j], 0, 0, 0);
                acc[i][j] = __builtin_amdgcn_mfma_f32_16x16x32_bf16(aR[i][1], bR0[j][1], acc[i][j], 0, 0, 0);
            }
        __builtin_amdgcn_s_setprio(0);
        __builtin_amdgcn_s_barrier();

        // ---- PH2: mh=0, nh=1 (reuse aR) ----
#pragma unroll
        for (int j = 0; j < 2; ++j) {
            bR1[j][0] = *(const s8v*)(Bcur + offB + 8192 + j * 1024 + ph0);
            bR1[j][1] = *(const s8v*)(Bcur + offB + 8192 + j * 1024 + ph1);
        }
        if (s < NT - 1) STG_B(Bnxt, 1, s + 1);
        __builtin_amdgcn_s_barrier();
        __builtin_amdgcn_s_setprio(1);
#pragma unroll
        for (int i = 0; i < 4; ++i)
#pragma unroll
            for (int j = 0; j < 2; ++j) {
                acc[i][2 + j] = __builtin_amdgcn_mfma_f32_16x16x32_bf16(aR[i][0], bR1[j][0], acc[i][2 + j], 0, 0, 0);
                acc[i][2 + j] = __builtin_amdgcn_mfma_f32_16x16x32_bf16(aR[i][1], bR1[j][1], acc[i][2 + j], 0, 0, 0);
            }
        __builtin_amdgcn_s_setprio(0);
        __builtin_amdgcn_s_barrier();

        // ---- PH3: mh=1, nh=0 (reuse bR0; overwrite aR; A-h0 now dead) ----
#pragma unroll
        for (int i = 0; i < 4; ++i) {
            aR[i][0] = *(const s8v*)(Acur + offA + 8192 + i * 1024 + ph0);
            aR[i][1] = *(const s8v*)(Acur + offA + 8192 + i * 1024 + ph1);
        }
        if (s < NT - 2) STG_A(Acur, 0, s + 2);
        __builtin_amdgcn_s_barrier();
        __builtin_amdgcn_s_setprio(1);
#pragma unroll
        for (int i = 0; i < 4; ++i)
#pragma unroll
            for (int j = 0; j < 2; ++j) {
                acc[4 + i][j] = __builtin_amdgcn_mfma_f32_16x16x32_bf16(aR[i][0], bR0[j][0], acc[4 + i][j], 0, 0, 0);
                acc[4 + i][j] = __builtin_amdgcn_mfma_f32_16x16x32_bf16(aR[i][1], bR0[j][1], acc[4 + i][j], 0, 0, 0);
            }
        __builtin_amdgcn_s_setprio(0);
        __builtin_amdgcn_s_barrier();

        // ---- PH4: mh=1, nh=1 (reuse aR, bR1; B-h0 now dead) ----
        if (s < NT - 2) STG_B(Bcur, 0, s + 2);
        __builtin_amdgcn_s_barrier();
        __builtin_amdgcn_s_setprio(1);
#pragma unroll
        for (int i = 0; i < 4; ++i)
#pragma unroll
            for (int j = 0; j < 2; ++j) {
                acc[4 + i][2 + j] = __builtin_amdgcn_mfma_f32_16x16x32_bf16(aR[i][0], bR1[j][0], acc[4 + i][2 + j], 0, 0, 0);
                acc[4 + i][2 + j] = __builtin_amdgcn_mfma_f32_16x16x32_bf16(aR[i][1], bR1[j][1], acc[4 + i][2 + j], 0, 0, 0);
            }
        __builtin_amdgcn_s_setprio(0);
        __builtin_amdgcn_s_barrier();
    }
#undef STG_A
#undef STG_B

    // ---- epilogue: C/D layout col = l15, row = quad*4 + rg (round-3 verified) ----
#pragma unroll
    for (int jg = 0; jg < 4; ++jg) {
        int n = n0 + wn * 64 + jg * 16 + l15;
        float bs = bias[n];
        if (MODE == 0) {
            u16* dst; int nn;
            if (n < 768)       { dst = oq;  nn = n; }
            else if (n < 1536) { dst = okk; nn = n - 768; }
            else               { dst = ov;  nn = n - 1536; }
#pragma unroll
            for (int ig = 0; ig < 8; ++ig) {
                int mrow = m0 + wm * 128 + ig * 16 + quad * 4;
#pragma unroll
                for (int rg = 0; rg < 4; ++rg)
                    dst[(size_t)(mrow + rg) * 768 + nn] = f2bf(acc[ig][jg][rg] + bs);
            }
        } else {
#pragma unroll
            for (int ig = 0; ig < 8; ++ig) {
                int mrow = m0 + wm * 128 + ig * 16 + quad * 4;
#pragma unroll
                for (int rg = 0; rg < 4; ++rg)
                    of[(size_t)(mrow + rg) * 768 + n] = acc[ig][jg][rg] + bs;
            }
        }
    }
}

// ---------------- V transpose: (192,1024,64) -> (192,64,1024) ----------------
__global__ void k_transpose_v(const u16* __restrict__ v, u16* __restrict__ vt) {
    __shared__ __attribute__((aligned(16))) u16 ts[64 * 80];
    int g = blockIdx.x >> 4;
    int l0 = (blockIdx.x & 15) << 6;
    const u16* vg = v + (size_t)g * 65536;
    u16* vtg = vt + (size_t)g * 65536;
    int tid = threadIdx.x;
#pragma unroll
    for (int c = tid; c < 512; c += 256) {
        int l = c >> 3, d0 = (c & 7) * 8;
        *(uint4*)(ts + l * 80 + d0) = *(const uint4*)(vg + (size_t)(l0 + l) * 64 + d0);
    }
    __syncthreads();
#pragma unroll
    for (int c = tid; c < 512; c += 256) {
        int d = c >> 3, lc = (c & 7) * 8;
        u16x8 tv;
#pragma unroll
        for (int i = 0; i < 8; ++i) tv[i] = ts[(lc + i) * 80 + d];
        *(u16x8*)(vtg + (size_t)d * 1024 + l0 + lc) = tv;
    }
}

// ---------------- flash attention per (group, 64-row q-tile) ----------------
// Round-4 verified: T12 in-register softmax + correct T14 (raw s_barrier +
// lgkmcnt-only drain; prefetch global loads stay in flight across barriers).
// q pre-scaled by 1/8; no online max (|s| <~ 8, exp overflow-safe in fp32).
#define KS2(r_, c_) ( ((r_) << 6) + (((((c_) >> 3) ^ ((r_) & 7)) & 7) << 3) + ((c_) & 7) )

__global__ __launch_bounds__(256) void k_attn(
    const u16* __restrict__ qb, const u16* __restrict__ kb,
    const u16* __restrict__ vt, u16* __restrict__ ctx)
{
    __shared__ __attribute__((aligned(16))) u16 Ks[128 * 64];    // 16 KB, XOR-swizzled
    __shared__ __attribute__((aligned(16))) u16 Vts[64 * 136];   // 17408 B

    const int g = blockIdx.x >> 4;
    const int q0 = (blockIdx.x & 15) << 6;
    const int tid = threadIdx.x, wv = tid >> 6;
    const int ln = tid & 63, l15 = ln & 15, quad = ln >> 4;
    const u16* qg = qb + (size_t)g * 65536;
    const u16* kg = kb + (size_t)g * 65536;
    const u16* vtg = vt + (size_t)g * 65536;

    // per-thread staging coordinates (4 uint4 each for K and Vt)
    const int krr = tid >> 3, kcb = (tid & 7) * 8;       // K: +i*32 rows
    const int vd = tid >> 4, vc0 = (tid & 15) * 8;       // Vt: +i*16 d-rows
    const u16* kgp = kg + (size_t)krr * 64 + kcb;
    const u16* vgp = vtg + (size_t)vd * 1024 + vc0;

    // prologue: issue tile-0 loads (named regs; static indexing only)
    uint4 kr0 = *(const uint4*)(kgp);
    uint4 kr1 = *(const uint4*)(kgp + 2048);
    uint4 kr2 = *(const uint4*)(kgp + 4096);
    uint4 kr3 = *(const uint4*)(kgp + 6144);
    uint4 vr0 = *(const uint4*)(vgp);
    uint4 vr1 = *(const uint4*)(vgp + 16384);
    uint4 vr2 = *(const uint4*)(vgp + 32768);
    uint4 vr3 = *(const uint4*)(vgp + 49152);

    // Q fragments straight from global (one-time; lane l15 = q-row wv*16+l15)
    const u16* qrow = qg + (size_t)(q0 + wv * 16 + l15) * 64 + quad * 8;
    s8v aQ0 = *(const s8v*)qrow;
    s8v aQ1 = *(const s8v*)(qrow + 32);

    f4v o[4] = {};
    float rsum = 0.f;

    for (int jt = 0; jt < 8; ++jt) {
        // barrier #1: all waves' prior-tile LDS reads retired. Raw barrier:
        // do NOT drain vmcnt (prefetch loads stay in flight).
        __builtin_amdgcn_s_barrier();
        __builtin_amdgcn_sched_barrier(0);

        // write staged tile: K 128x64 XOR-swizzled, Vt 64x128 (stride 136)
        *(uint4*)(Ks + KS2(krr,      kcb)) = kr0;
        *(uint4*)(Ks + KS2(krr + 32, kcb)) = kr1;
        *(uint4*)(Ks + KS2(krr + 64, kcb)) = kr2;
        *(uint4*)(Ks + KS2(krr + 96, kcb)) = kr3;
        *(uint4*)(Vts + (vd     ) * 136 + vc0) = vr0;
        *(uint4*)(Vts + (vd + 16) * 136 + vc0) = vr1;
        *(uint4*)(Vts + (vd + 32) * 136 + vc0) = vr2;
        *(uint4*)(Vts + (vd + 48) * 136 + vc0) = vr3;

        // prefetch next tile -> regs; stays in flight across barrier #2
        if (jt < 7) {
            const size_t koff = (size_t)(jt + 1) * 8192;   // 128 rows * 64
            const int voff = (jt + 1) * 128;
            kr0 = *(const uint4*)(kgp + koff);
            kr1 = *(const uint4*)(kgp + koff + 2048);
            kr2 = *(const uint4*)(kgp + koff + 4096);
            kr3 = *(const uint4*)(kgp + koff + 6144);
            vr0 = *(const uint4*)(vgp + voff);
            vr1 = *(const uint4*)(vgp + voff + 16384);
            vr2 = *(const uint4*)(vgp + voff + 32768);
            vr3 = *(const uint4*)(vgp + voff + 49152);
        }

        // barrier #2: own ds_writes done (lgkmcnt only -- vmcnt NOT drained)
        asm volatile("s_waitcnt lgkmcnt(0)" ::: "memory");
        __builtin_amdgcn_s_barrier();
        __builtin_amdgcn_sched_barrier(0);

        // swapped QK^T: s = mfma(Kfrag, Qfrag) -> lane l15 = q-row,
        // s[ns][rg] = S[wv*16+l15][k = ns*16 + quad*4 + rg]
        f4v s[8];
        __builtin_amdgcn_s_setprio(1);
#pragma unroll
        for (int ns = 0; ns < 8; ++ns) {
            int rK = ns * 16 + l15;
            s8v b0 = *(const s8v*)(Ks + KS2(rK, quad * 8));
            s8v b1 = *(const s8v*)(Ks + KS2(rK, quad * 8 + 32));
            f4v t = {};
            t = __builtin_amdgcn_mfma_f32_16x16x32_bf16(b0, aQ0, t, 0, 0, 0);
            t = __builtin_amdgcn_mfma_f32_16x16x32_bf16(b1, aQ1, t, 0, 0, 0);
            s[ns] = t;
        }
        __builtin_amdgcn_s_setprio(0);

        // p = exp(s); per-lane partial row sum (row = l15's q-row)
#pragma unroll
        for (int ns = 0; ns < 8; ++ns)
#pragma unroll
            for (int rg = 0; rg < 4; ++rg) {
                float p = __expf(s[ns][rg]);
                s[ns][rg] = p;
                rsum += p;
            }

        // in-register P -> PV A-fragment (T12): per 32-k block, 4 cvt_pk +
        // 2 permlane32_swap + 2 permlane16_swap -> lane quad q holds
        // k = 32ks + 8q + {0..7}.
        __builtin_amdgcn_s_setprio(1);
#pragma unroll
        for (int ks = 0; ks < 4; ++ks) {
            uint32_t a0, a1, c0, c1;
            asm("v_cvt_pk_bf16_f32 %0, %1, %2" : "=v"(a0) : "v"(s[2*ks][0]),   "v"(s[2*ks][1]));
            asm("v_cvt_pk_bf16_f32 %0, %1, %2" : "=v"(a1) : "v"(s[2*ks][2]),   "v"(s[2*ks][3]));
            asm("v_cvt_pk_bf16_f32 %0, %1, %2" : "=v"(c0) : "v"(s[2*ks+1][0]), "v"(s[2*ks+1][1]));
            asm("v_cvt_pk_bf16_f32 %0, %1, %2" : "=v"(c1) : "v"(s[2*ks+1][2]), "v"(s[2*ks+1][3]));
            asm("v_permlane32_swap_b32 %0, %1" : "+v"(a0), "+v"(c0));
            asm("v_permlane16_swap_b32 %0, %1" : "+v"(a0), "+v"(c0));
            asm("v_permlane32_swap_b32 %0, %1" : "+v"(a1), "+v"(c1));
            asm("v_permlane16_swap_b32 %0, %1" : "+v"(a1), "+v"(c1));
            u32x4 pk; pk.x = a0; pk.y = a1; pk.z = c0; pk.w = c1;
            s8v aP = __builtin_bit_cast(s8v, pk);
#pragma unroll
            for (int ds = 0; ds < 4; ++ds) {
                s8v bV = *(const s8v*)(Vts + (ds * 16 + l15) * 136 + ks * 32 + quad * 8);
                o[ds] = __builtin_amdgcn_mfma_f32_16x16x32_bf16(aP, bV, o[ds], 0, 0, 0);
            }
        }
        __builtin_amdgcn_s_setprio(0);
    }

    // full row sums: reduce per-lane partials across the 4 quads (same l15)
    rsum += __shfl_xor(rsum, 16, 64);
    rsum += __shfl_xor(rsum, 32, 64);

    // normalize + write ctx in (B,N,C) head-interleaved layout.
    const int b = g / 12, h = g % 12;
    u16* cbase = ctx + (size_t)b * 786432 + h * 64;
#pragma unroll
    for (int rg = 0; rg < 4; ++rg) {
        float rs = __shfl(rsum, 20 * quad + rg, 64);
        float inv = 1.0f / rs;
        int row = q0 + wv * 16 + quad * 4 + rg;
#pragma unroll
        for (int ds = 0; ds < 4; ++ds)
            cbase[(size_t)row * 768 + ds * 16 + l15] = f2bf(o[ds][rg] * inv);
    }
}

// ---------------- launcher ----------------
extern "C" void kernel_launch(void* const* d_in, const int* in_sizes, int n_in,
                              void* d_out, int out_size, void* d_ws, size_t ws_size,
                              hipStream_t stream) {
    const float* x  = (const float*)d_in[0];
    const float* Wq = (const float*)d_in[1];
    const float* bq = (const float*)d_in[2];
    const float* Wk = (const float*)d_in[3];
    const float* bk = (const float*)d_in[4];
    const float* Wv = (const float*)d_in[5];
    const float* bv = (const float*)d_in[6];
    const float* Wo = (const float*)d_in[7];
    const float* bo = (const float*)d_in[8];
    float* out = (float*)d_out;

    const size_t NTOK = (size_t)MTOT * EMBED;          // 12,582,912
    char* w = (char*)d_ws;
    u16* xb    = (u16*)w;              w += NTOK * 2;  // x bf16; reused as ctx
    u16* qb    = (u16*)w;              w += NTOK * 2;
    u16* kb    = (u16*)w;              w += NTOK * 2;
    u16* vb    = (u16*)w;              w += NTOK * 2;
    u16* vtb   = (u16*)w;              w += NTOK * 2;
    u16* wqkvT = (u16*)w;              w += (size_t)2304 * 768 * 2;
    u16* woT   = (u16*)w;              w += (size_t)768 * 768 * 2;
    float* bqkv = (float*)w;           w += 2304 * 4;
    u16* ctx = xb;                                      // reuse (x dead after GEMM1)

    k_pack<<<XBLOCKS + 9225, 256, 0, stream>>>(x, xb, (int)NTOK,
        Wq, Wk, Wv, Wo, bq, bk, bv, wqkvT, woT, bqkv);

    // GEMM1: M=16384, N=2304 -> 64 x 9 = 576 blocks (576 % 8 == 0)
    k_gemm8<0><<<576, 512, 0, stream>>>(xb, wqkvT, bqkv, qb, kb, vb, nullptr, 9);

    k_transpose_v<<<3072, 256, 0, stream>>>(vb, vtb);
    k_attn<<<3072, 256, 0, stream>>>(qb, kb, vtb, ctx);

    // GEMM2: M=16384, N=768 -> 64 x 3 = 192 blocks (192 % 8 == 0, single round)
    k_gemm8<1><<<192, 512, 0, stream>>>(ctx, woT, bo, nullptr, nullptr, nullptr, out, 3);
}

// Round 6
// 321.807 us; speedup vs baseline: 1.0338x; 1.0338x over previous
//
#include <hip/hip_runtime.h>
#include <hip/hip_bf16.h>
#include <cstdint>
#include <cstddef>

typedef unsigned short u16;
typedef __attribute__((ext_vector_type(8))) short s8v;    // 8 x bf16 = 4 VGPR
typedef __attribute__((ext_vector_type(4))) float f4v;    // 16x16 MFMA acc
typedef __attribute__((ext_vector_type(8))) u16 u16x8;
typedef __attribute__((ext_vector_type(4))) uint32_t u32x4;

#define AS1 __attribute__((address_space(1)))
#define AS3 __attribute__((address_space(3)))

// ---- constants ----
#define BATCH 16
#define SEQ   1024
#define EMBED 768
#define HEADS 12
#define DH    64
#define MTOT  (BATCH*SEQ)       // 16384

__device__ __forceinline__ u16 f2bf(float f) {      // RNE fp32 -> bf16
    union { float f; uint32_t u; } v; v.f = f;
    uint32_t r = v.u + 0x7fffu + ((v.u >> 16) & 1u);
    return (u16)(r >> 16);
}

__device__ __forceinline__ void gll16(const u16* g, u16* l) {
    __builtin_amdgcn_global_load_lds((AS1 void*)g, (AS3 void*)l, 16, 0, 0);
}

// ---------------- fused pack ----------------
// x -> bf16 (coalesced); weights transpose+bf16 via 64x64 LDS tiles (round-6:
// replaces 2-byte stride-1536B scattered writes, ~150 MB partial-line RMW);
// biases. Wq/bq pre-scaled by 0.125 (folds 1/sqrt(Dh) into Q proj).
#define XBLOCKS 12288
#define TBLOCKS 576          // 432 QKV tiles (36 n x 12 k) + 144 Wo tiles (12 x 12)
__global__ void k_pack(const float* __restrict__ x, u16* __restrict__ xb, int nx,
                       const float* __restrict__ Wq, const float* __restrict__ Wk,
                       const float* __restrict__ Wv, const float* __restrict__ Wo,
                       const float* __restrict__ bq, const float* __restrict__ bk,
                       const float* __restrict__ bv,
                       u16* __restrict__ wqkvT, u16* __restrict__ woT,
                       float* __restrict__ bqkv)
{
    __shared__ __attribute__((aligned(16))) u16 ts[64 * 80];
    const int tid = threadIdx.x;
    if (blockIdx.x < XBLOCKS) {
        int i = (blockIdx.x * 256 + tid) * 4;
        if (i + 3 < nx) {
            float4 f = *(const float4*)(x + i);
            ushort4 o;
            o.x = f2bf(f.x); o.y = f2bf(f.y); o.z = f2bf(f.z); o.w = f2bf(f.w);
            *(ushort4*)(xb + i) = o;
        }
        return;
    }
    int tb = blockIdx.x - XBLOCKS;
    if (tb < TBLOCKS) {
        // 64x64 tile transpose: out[n][k] = src[k][nn] * sc (bf16)
        const float* src; u16* dst; int n0, k0, nn0; float sc;
        if (tb < 432) {
            int nt = tb % 36, kt = tb / 36;
            n0 = nt * 64; k0 = kt * 64; dst = wqkvT;
            if (n0 < 768)       { src = Wq; nn0 = n0;        sc = 0.125f; }
            else if (n0 < 1536) { src = Wk; nn0 = n0 - 768;  sc = 1.0f;   }
            else                { src = Wv; nn0 = n0 - 1536; sc = 1.0f;   }
        } else {
            int tb2 = tb - 432;
            int nt = tb2 % 12, kt = tb2 / 12;
            n0 = nt * 64; k0 = kt * 64; nn0 = n0; sc = 1.0f;
            src = Wo; dst = woT;
        }
        const int r = tid >> 2, cb = (tid & 3) * 16;
        // load: src row k0+r, cols nn0+cb..+15 (coalesced f32); store transposed
        // into LDS ts[col][row] (stride 80 keeps u16x8 out-reads 16B-aligned)
#pragma unroll
        for (int i = 0; i < 4; ++i) {
            float4 f = *(const float4*)(src + (size_t)(k0 + r) * 768 + nn0 + cb + i * 4);
            ts[(cb + i * 4 + 0) * 80 + r] = f2bf(f.x * sc);
            ts[(cb + i * 4 + 1) * 80 + r] = f2bf(f.y * sc);
            ts[(cb + i * 4 + 2) * 80 + r] = f2bf(f.z * sc);
            ts[(cb + i * 4 + 3) * 80 + r] = f2bf(f.w * sc);
        }
        __syncthreads();
        // out: row n0+r (n-local r), cols k0+cb..+15 -- coalesced u16x8 stores
#pragma unroll
        for (int j = 0; j < 2; ++j) {
            u16x8 tv = *(const u16x8*)(ts + r * 80 + cb + j * 8);
            *(u16x8*)(dst + (size_t)(n0 + r) * 768 + k0 + cb + j * 8) = tv;
        }
        return;
    }
    int t3 = (tb - TBLOCKS) * 256 + tid;
    if (t3 < 2304) {
        bqkv[t3] = (t3 < 768) ? bq[t3] * 0.125f
                 : ((t3 < 1536) ? bk[t3 - 768] : bv[t3 - 1536]);
    }
}

// ---------------- GEMM: C[M x N] = A[M x 768] * BT[N x 768]^T + bias ----------------
// 128x128 tile, BK=32, 256 thr (4 waves 2x2), wave tile 64x64 = 4x4 MFMA 16x16x32.
// (round-4 verified best; 8-phase 256^2 port reached only parity -- short K=768
//  amortizes its prologue poorly and 1 block/CU removes cross-block overlap.)
template<int MODE>
__global__ __launch_bounds__(256) void k_gemm(
    const u16* __restrict__ A, const u16* __restrict__ BT,
    const float* __restrict__ bias,
    u16* __restrict__ oq, u16* __restrict__ okk, u16* __restrict__ ov,
    float* __restrict__ of)
{
    __shared__ __attribute__((aligned(16))) u16 As[128 * 32];
    __shared__ __attribute__((aligned(16))) u16 Bs[128 * 32];
    const int tid = threadIdx.x;
    const int m0 = blockIdx.x * 128;
    const int n0 = blockIdx.y * 128;
    const int wv = tid >> 6;
    const int ln = tid & 63;
    const int l15 = ln & 15, quad = ln >> 4;
    const int wm = (wv >> 1) * 64, wn = (wv & 1) * 64;
    const int r = tid >> 2, c8 = (tid & 3) * 8;

    const u16* gA0 = A + (size_t)(m0 + r) * 768 + c8;
    const u16* gA1 = gA0 + 64 * 768;
    const u16* gB0 = BT + (size_t)(n0 + r) * 768 + c8;
    const u16* gB1 = gB0 + 64 * 768;
    u16* lA0 = As + wv * 512;
    u16* lA1 = As + 2048 + wv * 512;
    u16* lB0 = Bs + wv * 512;
    u16* lB1 = Bs + 2048 + wv * 512;

    f4v acc[4][4] = {};

    for (int kt = 0; kt < 24; ++kt) {
        const int ko = kt * 32;
        gll16(gA0 + ko, lA0);
        gll16(gA1 + ko, lA1);
        gll16(gB0 + ko, lB0);
        gll16(gB1 + ko, lB1);
        __syncthreads();
        s8v aF[4], bF[4];
#pragma unroll
        for (int i = 0; i < 4; ++i)
            aF[i] = *(const s8v*)(As + (wm + i * 16 + l15) * 32 + quad * 8);
#pragma unroll
        for (int j = 0; j < 4; ++j)
            bF[j] = *(const s8v*)(Bs + (wn + j * 16 + l15) * 32 + quad * 8);
#pragma unroll
        for (int i = 0; i < 4; ++i)
#pragma unroll
            for (int j = 0; j < 4; ++j)
                acc[i][j] = __builtin_amdgcn_mfma_f32_16x16x32_bf16(aF[i], bF[j], acc[i][j], 0, 0, 0);
        __syncthreads();
    }

    // epilogue: C/D layout col = l15, row = quad*4 + reg (verified)
#pragma unroll
    for (int j = 0; j < 4; ++j) {
        int n = n0 + wn + j * 16 + l15;
        float bs = bias[n];
        if (MODE == 0) {
            u16* dst; int nn;
            if (n < 768)       { dst = oq;  nn = n; }
            else if (n < 1536) { dst = okk; nn = n - 768; }
            else               { dst = ov;  nn = n - 1536; }
#pragma unroll
            for (int i = 0; i < 4; ++i) {
                int mrow = m0 + wm + i * 16 + quad * 4;
#pragma unroll
                for (int rg = 0; rg < 4; ++rg)
                    dst[(size_t)(mrow + rg) * 768 + nn] = f2bf(acc[i][j][rg] + bs);
            }
        } else {
#pragma unroll
            for (int i = 0; i < 4; ++i) {
                int mrow = m0 + wm + i * 16 + quad * 4;
#pragma unroll
                for (int rg = 0; rg < 4; ++rg)
                    of[(size_t)(mrow + rg) * 768 + n] = acc[i][j][rg] + bs;
            }
        }
    }
}

// ---------------- V transpose: (192,1024,64) -> (192,64,1024) ----------------
__global__ void k_transpose_v(const u16* __restrict__ v, u16* __restrict__ vt) {
    __shared__ __attribute__((aligned(16))) u16 ts[64 * 80];
    int g = blockIdx.x >> 4;
    int l0 = (blockIdx.x & 15) << 6;
    const u16* vg = v + (size_t)g * 65536;
    u16* vtg = vt + (size_t)g * 65536;
    int tid = threadIdx.x;
#pragma unroll
    for (int c = tid; c < 512; c += 256) {
        int l = c >> 3, d0 = (c & 7) * 8;
        *(uint4*)(ts + l * 80 + d0) = *(const uint4*)(vg + (size_t)(l0 + l) * 64 + d0);
    }
    __syncthreads();
#pragma unroll
    for (int c = tid; c < 512; c += 256) {
        int d = c >> 3, lc = (c & 7) * 8;
        u16x8 tv;
#pragma unroll
        for (int i = 0; i < 8; ++i) tv[i] = ts[(lc + i) * 80 + d];
        *(u16x8*)(vtg + (size_t)d * 1024 + l0 + lc) = tv;
    }
}

// ---------------- flash attention per (group, 128-row q-tile) ----------------
// Round-6: 2 q-row-sets per wave (32 q-rows). Each K/V fragment read from LDS
// feeds TWO MFMAs (one per set) -> per-q-row LDS traffic halves (attn was
// LDS-read-bound: ~71 us floor at 16 rows/wave, ~36 us at 32). Staging,
// swizzles, T12 repack, T14 raw-barrier prefetch: identical to round-4
// (verified). q pre-scaled by 1/8; no online max (|s| <~ 8, fp32-safe).
#define KS2(r_, c_) ( ((r_) << 6) + (((((c_) >> 3) ^ ((r_) & 7)) & 7) << 3) + ((c_) & 7) )

__global__ __launch_bounds__(256) void k_attn(
    const u16* __restrict__ qb, const u16* __restrict__ kb,
    const u16* __restrict__ vt, u16* __restrict__ ctx)
{
    __shared__ __attribute__((aligned(16))) u16 Ks[128 * 64];    // 16 KB, XOR-swizzled
    __shared__ __attribute__((aligned(16))) u16 Vts[64 * 136];   // 17408 B

    const int g = blockIdx.x >> 3;
    const int q0 = (blockIdx.x & 7) << 7;
    const int tid = threadIdx.x, wv = tid >> 6;
    const int ln = tid & 63, l15 = ln & 15, quad = ln >> 4;
    const u16* qg = qb + (size_t)g * 65536;
    const u16* kg = kb + (size_t)g * 65536;
    const u16* vtg = vt + (size_t)g * 65536;

    // per-thread staging coordinates (4 uint4 each for K and Vt)
    const int krr = tid >> 3, kcb = (tid & 7) * 8;       // K: +i*32 rows
    const int vd = tid >> 4, vc0 = (tid & 15) * 8;       // Vt: +i*16 d-rows
    const u16* kgp = kg + (size_t)krr * 64 + kcb;
    const u16* vgp = vtg + (size_t)vd * 1024 + vc0;

    // prologue: issue tile-0 loads (named regs; static indexing only)
    uint4 kr0 = *(const uint4*)(kgp);
    uint4 kr1 = *(const uint4*)(kgp + 2048);
    uint4 kr2 = *(const uint4*)(kgp + 4096);
    uint4 kr3 = *(const uint4*)(kgp + 6144);
    uint4 vr0 = *(const uint4*)(vgp);
    uint4 vr1 = *(const uint4*)(vgp + 16384);
    uint4 vr2 = *(const uint4*)(vgp + 32768);
    uint4 vr3 = *(const uint4*)(vgp + 49152);

    // Q fragments, two 16-row sets per wave (rows q0 + wv*32 + set*16 + l15)
    const u16* qrow = qg + (size_t)(q0 + wv * 32 + l15) * 64 + quad * 8;
    s8v aQ00 = *(const s8v*)qrow;
    s8v aQ01 = *(const s8v*)(qrow + 32);
    s8v aQ10 = *(const s8v*)(qrow + 1024);        // +16 rows * 64
    s8v aQ11 = *(const s8v*)(qrow + 1024 + 32);

    f4v o0[4] = {}, o1[4] = {};
    float rsum0 = 0.f, rsum1 = 0.f;

    for (int jt = 0; jt < 8; ++jt) {
        // barrier #1: all waves' prior-tile LDS reads retired. Raw barrier:
        // do NOT drain vmcnt (prefetch loads stay in flight).
        __builtin_amdgcn_s_barrier();
        __builtin_amdgcn_sched_barrier(0);

        // write staged tile: K 128x64 XOR-swizzled, Vt 64x128 (stride 136)
        *(uint4*)(Ks + KS2(krr,      kcb)) = kr0;
        *(uint4*)(Ks + KS2(krr + 32, kcb)) = kr1;
        *(uint4*)(Ks + KS2(krr + 64, kcb)) = kr2;
        *(uint4*)(Ks + KS2(krr + 96, kcb)) = kr3;
        *(uint4*)(Vts + (vd     ) * 136 + vc0) = vr0;
        *(uint4*)(Vts + (vd + 16) * 136 + vc0) = vr1;
        *(uint4*)(Vts + (vd + 32) * 136 + vc0) = vr2;
        *(uint4*)(Vts + (vd + 48) * 136 + vc0) = vr3;

        // prefetch next tile -> regs; stays in flight across barrier #2
        if (jt < 7) {
            const size_t koff = (size_t)(jt + 1) * 8192;   // 128 rows * 64
            const int voff = (jt + 1) * 128;
            kr0 = *(const uint4*)(kgp + koff);
            kr1 = *(const uint4*)(kgp + koff + 2048);
            kr2 = *(const uint4*)(kgp + koff + 4096);
            kr3 = *(const uint4*)(kgp + koff + 6144);
            vr0 = *(const uint4*)(vgp + voff);
            vr1 = *(const uint4*)(vgp + voff + 16384);
            vr2 = *(const uint4*)(vgp + voff + 32768);
            vr3 = *(const uint4*)(vgp + voff + 49152);
        }

        // barrier #2: own ds_writes done (lgkmcnt only -- vmcnt NOT drained)
        asm volatile("s_waitcnt lgkmcnt(0)" ::: "memory");
        __builtin_amdgcn_s_barrier();
        __builtin_amdgcn_sched_barrier(0);

        // swapped QK^T: each K-frag pair (b0,b1) feeds BOTH q-sets.
        // s{0,1}[ns][rg] = S[q-set row][k = ns*16 + quad*4 + rg]
        f4v s0[8], s1[8];
        __builtin_amdgcn_s_setprio(1);
#pragma unroll
        for (int ns = 0; ns < 8; ++ns) {
            int rK = ns * 16 + l15;
            s8v b0 = *(const s8v*)(Ks + KS2(rK, quad * 8));
            s8v b1 = *(const s8v*)(Ks + KS2(rK, quad * 8 + 32));
            f4v t0 = {};
            t0 = __builtin_amdgcn_mfma_f32_16x16x32_bf16(b0, aQ00, t0, 0, 0, 0);
            t0 = __builtin_amdgcn_mfma_f32_16x16x32_bf16(b1, aQ01, t0, 0, 0, 0);
            s0[ns] = t0;
            f4v t1 = {};
            t1 = __builtin_amdgcn_mfma_f32_16x16x32_bf16(b0, aQ10, t1, 0, 0, 0);
            t1 = __builtin_amdgcn_mfma_f32_16x16x32_bf16(b1, aQ11, t1, 0, 0, 0);
            s1[ns] = t1;
        }
        __builtin_amdgcn_s_setprio(0);

        // softmax + T12 repack, set 0 then set 1 (limits register peak)
        s8v aP0[4], aP1[4];
#pragma unroll
        for (int ns = 0; ns < 8; ++ns)
#pragma unroll
            for (int rg = 0; rg < 4; ++rg) {
                float p = __expf(s0[ns][rg]);
                s0[ns][rg] = p;
                rsum0 += p;
            }
#pragma unroll
        for (int ks = 0; ks < 4; ++ks) {
            uint32_t a0, a1, c0, c1;
            asm("v_cvt_pk_bf16_f32 %0, %1, %2" : "=v"(a0) : "v"(s0[2*ks][0]),   "v"(s0[2*ks][1]));
            asm("v_cvt_pk_bf16_f32 %0, %1, %2" : "=v"(a1) : "v"(s0[2*ks][2]),   "v"(s0[2*ks][3]));
            asm("v_cvt_pk_bf16_f32 %0, %1, %2" : "=v"(c0) : "v"(s0[2*ks+1][0]), "v"(s0[2*ks+1][1]));
            asm("v_cvt_pk_bf16_f32 %0, %1, %2" : "=v"(c1) : "v"(s0[2*ks+1][2]), "v"(s0[2*ks+1][3]));
            asm("v_permlane32_swap_b32 %0, %1" : "+v"(a0), "+v"(c0));
            asm("v_permlane16_swap_b32 %0, %1" : "+v"(a0), "+v"(c0));
            asm("v_permlane32_swap_b32 %0, %1" : "+v"(a1), "+v"(c1));
            asm("v_permlane16_swap_b32 %0, %1" : "+v"(a1), "+v"(c1));
            u32x4 pk; pk.x = a0; pk.y = a1; pk.z = c0; pk.w = c1;
            aP0[ks] = __builtin_bit_cast(s8v, pk);
        }
#pragma unroll
        for (int ns = 0; ns < 8; ++ns)
#pragma unroll
            for (int rg = 0; rg < 4; ++rg) {
                float p = __expf(s1[ns][rg]);
                s1[ns][rg] = p;
                rsum1 += p;
            }
#pragma unroll
        for (int ks = 0; ks < 4; ++ks) {
            uint32_t a0, a1, c0, c1;
            asm("v_cvt_pk_bf16_f32 %0, %1, %2" : "=v"(a0) : "v"(s1[2*ks][0]),   "v"(s1[2*ks][1]));
            asm("v_cvt_pk_bf16_f32 %0, %1, %2" : "=v"(a1) : "v"(s1[2*ks][2]),   "v"(s1[2*ks][3]));
            asm("v_cvt_pk_bf16_f32 %0, %1, %2" : "=v"(c0) : "v"(s1[2*ks+1][0]), "v"(s1[2*ks+1][1]));
            asm("v_cvt_pk_bf16_f32 %0, %1, %2" : "=v"(c1) : "v"(s1[2*ks+1][2]), "v"(s1[2*ks+1][3]));
            asm("v_permlane32_swap_b32 %0, %1" : "+v"(a0), "+v"(c0));
            asm("v_permlane16_swap_b32 %0, %1" : "+v"(a0), "+v"(c0));
            asm("v_permlane32_swap_b32 %0, %1" : "+v"(a1), "+v"(c1));
            asm("v_permlane16_swap_b32 %0, %1" : "+v"(a1), "+v"(c1));
            u32x4 pk; pk.x = a0; pk.y = a1; pk.z = c0; pk.w = c1;
            aP1[ks] = __builtin_bit_cast(s8v, pk);
        }

        // O += P V : each bV read feeds BOTH sets' MFMAs
        __builtin_amdgcn_s_setprio(1);
#pragma unroll
        for (int ks = 0; ks < 4; ++ks)
#pragma unroll
            for (int ds = 0; ds < 4; ++ds) {
                s8v bV = *(const s8v*)(Vts + (ds * 16 + l15) * 136 + ks * 32 + quad * 8);
                o0[ds] = __builtin_amdgcn_mfma_f32_16x16x32_bf16(aP0[ks], bV, o0[ds], 0, 0, 0);
                o1[ds] = __builtin_amdgcn_mfma_f32_16x16x32_bf16(aP1[ks], bV, o1[ds], 0, 0, 0);
            }
        __builtin_amdgcn_s_setprio(0);
    }

    // full row sums: reduce per-lane partials across the 4 quads (same l15)
    rsum0 += __shfl_xor(rsum0, 16, 64);
    rsum0 += __shfl_xor(rsum0, 32, 64);
    rsum1 += __shfl_xor(rsum1, 16, 64);
    rsum1 += __shfl_xor(rsum1, 32, 64);

    // normalize + write ctx in (B,N,C) head-interleaved layout.
    // output row (set s) = q0 + wv*32 + s*16 + quad*4 + rg; rowsum of q-row
    // l15'=quad*4+rg lives (replicated over quads) at lane 16*quad + (quad*4+rg).
    const int b = g / 12, h = g % 12;
    u16* cbase = ctx + (size_t)b * 786432 + h * 64;
#pragma unroll
    for (int rg = 0; rg < 4; ++rg) {
        int row0 = q0 + wv * 32 + quad * 4 + rg;
        float inv0 = 1.0f / __shfl(rsum0, 20 * quad + rg, 64);
#pragma unroll
        for (int ds = 0; ds < 4; ++ds)
            cbase[(size_t)row0 * 768 + ds * 16 + l15] = f2bf(o0[ds][rg] * inv0);
        int row1 = row0 + 16;
        float inv1 = 1.0f / __shfl(rsum1, 20 * quad + rg, 64);
#pragma unroll
        for (int ds = 0; ds < 4; ++ds)
            cbase[(size_t)row1 * 768 + ds * 16 + l15] = f2bf(o1[ds][rg] * inv1);
    }
}

// ---------------- launcher ----------------
extern "C" void kernel_launch(void* const* d_in, const int* in_sizes, int n_in,
                              void* d_out, int out_size, void* d_ws, size_t ws_size,
                              hipStream_t stream) {
    const float* x  = (const float*)d_in[0];
    const float* Wq = (const float*)d_in[1];
    const float* bq = (const float*)d_in[2];
    const float* Wk = (const float*)d_in[3];
    const float* bk = (const float*)d_in[4];
    const float* Wv = (const float*)d_in[5];
    const float* bv = (const float*)d_in[6];
    const float* Wo = (const float*)d_in[7];
    const float* bo = (const float*)d_in[8];
    float* out = (float*)d_out;

    const size_t NTOK = (size_t)MTOT * EMBED;          // 12,582,912
    char* w = (char*)d_ws;
    u16* xb    = (u16*)w;              w += NTOK * 2;  // x bf16; reused as ctx
    u16* qb    = (u16*)w;              w += NTOK * 2;
    u16* kb    = (u16*)w;              w += NTOK * 2;
    u16* vb    = (u16*)w;              w += NTOK * 2;
    u16* vtb   = (u16*)w;              w += NTOK * 2;
    u16* wqkvT = (u16*)w;              w += (size_t)2304 * 768 * 2;
    u16* woT   = (u16*)w;              w += (size_t)768 * 768 * 2;
    float* bqkv = (float*)w;           w += 2304 * 4;
    u16* ctx = xb;                                      // reuse (x dead after GEMM1)

    k_pack<<<XBLOCKS + TBLOCKS + 9, 256, 0, stream>>>(x, xb, (int)NTOK,
        Wq, Wk, Wv, Wo, bq, bk, bv, wqkvT, woT, bqkv);

    dim3 g1(128, 18);
    k_gemm<0><<<g1, 256, 0, stream>>>(xb, wqkvT, bqkv, qb, kb, vb, nullptr);

    k_transpose_v<<<3072, 256, 0, stream>>>(vb, vtb);
    k_attn<<<1536, 256, 0, stream>>>(qb, kb, vtb, ctx);

    dim3 g2(128, 6);
    k_gemm<1><<<g2, 256, 0, stream>>>(ctx, woT, bo, nullptr, nullptr, nullptr, out);
}